// Round 3
// baseline (106.284 us; speedup 1.0000x reference)
//
#include <hip/hip_runtime.h>

typedef __attribute__((ext_vector_type(8))) __bf16 bf16x8;
typedef __attribute__((ext_vector_type(4))) float f32x4;

#define KC 64
#define NSL 4          // K-slices per t
#define NCH 8          // chunks per slice: 512 / 64
#define REC 12416      // floats per slice record: 3*4096 + 64 + 64
#define PBASE 12544    // partials base (after dmat|Gnn|Gaa|Rn|Ra|Sn|Sa)

__device__ __forceinline__ unsigned short f2bf(float x) {
    unsigned u = __float_as_uint(x);
    u += 0x7FFFu + ((u >> 16) & 1u);   // round-to-nearest-even
    return (unsigned short)(u >> 16);
}

// ws head (floats): dmat[4096] | Gnn[4096] | Gaa[4096] | Rn[64] | Ra[64] | Sn[64] | Sa[64]
// then 800 slice records: accD[4096] | accNN[4096] | accAA[4096] | n2p[64] | a2p[64]

__global__ __launch_bounds__(256, 4) void cl_partial(const float* __restrict__ feats,
                                                     float* __restrict__ ws)
{
    float* Rn = ws + 12288;
    float* Ra = ws + 12352;
    float* Sn = ws + 12416;
    float* Sa = ws + 12480;

    const int b   = blockIdx.x;          // 0..799
    const int t   = b >> 2;              // 0..199
    const int sl  = b & 3;               // K-slice
    const int tid = threadIdx.x;
    const int row = tid >> 2;            // loader row 0..63
    const int q   = tid & 3;             // 4 loader lanes per row
    const int w   = tid >> 6;            // wave 0..3
    const int r16 = tid & 15;
    const int kg  = (tid & 63) >> 4;

    __shared__ __align__(16) unsigned short lN[64][64];   // 8 KB
    __shared__ __align__(16) unsigned short lA[64][64];   // 8 KB

    const size_t kbase = (size_t)t * 2048 + (size_t)sl * 512;
    const float* gN = feats + (size_t)row        * 409600 + kbase;
    const float* gA = feats + (size_t)(64 + row) * 409600 + kbase;

    float nq = 0.f, ns = 0.f, aq = 0.f, ar = 0.f, asum = 0.f;
    f32x4 accD[4], accNN[4], accAA[4];
    const f32x4 zero = {0.f, 0.f, 0.f, 0.f};
    #pragma unroll
    for (int j = 0; j < 4; ++j) { accD[j] = zero; accNN[j] = zero; accAA[j] = zero; }

    const int swz  = (row & 7) << 3;
    const int rswz = (r16 & 7) << 3;

    for (int c = 0; c < NCH; ++c) {
        const int ko = c * KC;
        float4 rNv[4], rAv[4];
        #pragma unroll
        for (int s = 0; s < 4; ++s) {
            const int k = 4 * q + 16 * s;
            rNv[s] = *(const float4*)(gN + ko + k);
            rAv[s] = *(const float4*)(gA + ko + k);
        }
        __syncthreads();   // previous chunk's MFMA reads done
        #pragma unroll
        for (int s = 0; s < 4; ++s) {
            const int k = 4 * q + 16 * s;
            float4 vn = rNv[s], va = rAv[s];
            nq += vn.x*vn.x + vn.y*vn.y + vn.z*vn.z + vn.w*vn.w;
            ns += vn.x + vn.y + vn.z + vn.w;
            const float e = 1e-6f;
            float ax = va.x - e, ay = va.y - e, az = va.z - e, aw = va.w - e;
            aq += ax*ax + ay*ay + az*az + aw*aw;                 // (a-eps)^2 for hinge
            ar += va.x*va.x + va.y*va.y + va.z*va.z + va.w*va.w; // raw a^2 for Ra
            asum += va.x + va.y + va.z + va.w;
            ushort4 pn; pn.x=f2bf(vn.x); pn.y=f2bf(vn.y); pn.z=f2bf(vn.z); pn.w=f2bf(vn.w);
            ushort4 pa; pa.x=f2bf(va.x); pa.y=f2bf(va.y); pa.z=f2bf(va.z); pa.w=f2bf(va.w);
            *(ushort4*)&lN[row][k ^ swz] = pn;
            *(ushort4*)&lA[row][k ^ swz] = pa;
        }
        __syncthreads();
        #pragma unroll
        for (int ks = 0; ks < 2; ++ks) {
            const int kb = ks * 32 + kg * 8;
            bf16x8 aN = *(const bf16x8*)&lN[w*16 + r16][kb ^ rswz];
            bf16x8 aA = *(const bf16x8*)&lA[w*16 + r16][kb ^ rswz];
            #pragma unroll
            for (int jt = 0; jt < 4; ++jt) {
                bf16x8 bN = *(const bf16x8*)&lN[jt*16 + r16][kb ^ rswz];
                bf16x8 bA = *(const bf16x8*)&lA[jt*16 + r16][kb ^ rswz];
                accD[jt]  = __builtin_amdgcn_mfma_f32_16x16x32_bf16(aN, bA, accD[jt],  0, 0, 0);
                accNN[jt] = __builtin_amdgcn_mfma_f32_16x16x32_bf16(aN, bN, accNN[jt], 0, 0, 0);
                accAA[jt] = __builtin_amdgcn_mfma_f32_16x16x32_bf16(aA, bA, accAA[jt], 0, 0, 0);
            }
        }
    }

    // per-(row,t,slice) norm partials across the 4 loader lanes
    nq   += __shfl_xor(nq, 1);   nq   += __shfl_xor(nq, 2);
    aq   += __shfl_xor(aq, 1);   aq   += __shfl_xor(aq, 2);
    ns   += __shfl_xor(ns, 1);   ns   += __shfl_xor(ns, 2);
    ar   += __shfl_xor(ar, 1);   ar   += __shfl_xor(ar, 2);
    asum += __shfl_xor(asum, 1); asum += __shfl_xor(asum, 2);

    float* rec = ws + PBASE + (size_t)b * REC;
    if (q == 0) {
        rec[12288 + row] = nq;     // n2 partial (hinge)
        rec[12352 + row] = aq;     // a2eps partial (hinge)
        atomicAdd(&Rn[row], nq);
        atomicAdd(&Ra[row], ar);
        atomicAdd(&Sn[row], ns);
        atomicAdd(&Sa[row], asum);
    }

    // store raw partial matrices (exclusive region, no atomics)
    #pragma unroll
    for (int jt = 0; jt < 4; ++jt) {
        #pragma unroll
        for (int r = 0; r < 4; ++r) {
            const int ij = (w*16 + kg*4 + r) * 64 + jt*16 + r16;
            rec[ij]        = accD[jt][r];
            rec[4096 + ij] = accNN[jt][r];
            rec[8192 + ij] = accAA[jt][r];
        }
    }
}

// grid: 20 t-groups (10 t each) x 16 ij-blocks = 320 blocks
__global__ __launch_bounds__(256) void cl_combine(float* __restrict__ ws)
{
    const int bidx = blockIdx.x;
    const int g    = bidx >> 4;          // 0..19
    const int jb   = bidx & 15;          // 0..15
    const int tid  = threadIdx.x;
    const int ij   = jb * 256 + tid;     // 0..4095
    const int i    = ij >> 6;
    const int j    = ij & 63;

    const float* P = ws + PBASE;
    float dsum = 0.f, gnn = 0.f, gaa = 0.f;

    const int t0 = g * 10;
    #pragma unroll 2
    for (int t = t0; t < t0 + 10; ++t) {
        const float* r0 = P + (size_t)(t*4 + 0) * REC;
        const float* r1 = P + (size_t)(t*4 + 1) * REC;
        const float* r2 = P + (size_t)(t*4 + 2) * REC;
        const float* r3 = P + (size_t)(t*4 + 3) * REC;
        float cross = r0[ij] + r1[ij] + r2[ij] + r3[ij];
        gnn += r0[4096+ij] + r1[4096+ij] + r2[4096+ij] + r3[4096+ij];
        gaa += r0[8192+ij] + r1[8192+ij] + r2[8192+ij] + r3[8192+ij];
        float n2 = r0[12288+i] + r1[12288+i] + r2[12288+i] + r3[12288+i];
        float a2 = r0[12352+j] + r1[12352+j] + r2[12352+j] + r3[12352+j];
        float dist2 = fmaxf(n2 + a2 - 2.f * cross, 0.f);
        float v = fmaxf(200.f - sqrtf(dist2), 0.f);
        dsum += v * v;
    }
    atomicAdd(&ws[ij],        dsum * 0.005f);   // dmat, 1/200
    atomicAdd(&ws[4096 + ij], gnn);
    atomicAdd(&ws[8192 + ij], gaa);
}

__global__ __launch_bounds__(256) void cl_final(const float* __restrict__ ws,
                                                float* __restrict__ out)
{
    const float* dmat = ws;
    const float* Gnn  = ws + 4096;
    const float* Gaa  = ws + 8192;
    const float* Rn   = ws + 12288;
    const float* Ra   = ws + 12352;
    const float* Sn   = ws + 12416;
    const float* Sa   = ws + 12480;

    const int tid = threadIdx.x;
    __shared__ float wv[4];
    __shared__ int   wi[4];
    __shared__ int   sIdx;

    float bv = 3.4e38f; int bi = 1 << 30;
    for (int k = tid; k < 4096; k += 256) {
        float v = dmat[k];
        if (v < bv) { bv = v; bi = k; }
    }
    #pragma unroll
    for (int off = 32; off > 0; off >>= 1) {
        float ov = __shfl_xor(bv, off);
        int   oi = __shfl_xor(bi, off);
        if (ov < bv || (ov == bv && oi < bi)) { bv = ov; bi = oi; }
    }
    if ((tid & 63) == 0) { wv[tid >> 6] = bv; wi[tid >> 6] = bi; }
    __syncthreads();
    if (tid == 0) {
        float fv = wv[0]; int fi = wi[0];
        for (int k = 1; k < 4; ++k)
            if (wv[k] < fv || (wv[k] == fv && wi[k] < fi)) { fv = wv[k]; fi = wi[k]; }
        sIdx = fi;
    }
    __syncthreads();
    const int idx = sIdx;
    const int mn = idx >> 6;
    const int ma = idx & 63;

    if (tid < 64) {
        float tn = 0.f, ta = 0.f;
        if (tid != mn)
            tn = Rn[tid] + Rn[mn] - 2.f * Gnn[tid*64 + mn]
               + 2e-6f * (Sn[tid] - Sn[mn]) + 409600.f * 1e-12f;
        if (tid != ma)
            ta = Ra[tid] + Ra[ma] - 2.f * Gaa[tid*64 + ma]
               + 2e-6f * (Sa[tid] - Sa[ma]) + 409600.f * 1e-12f;
        float s = tn + ta;
        #pragma unroll
        for (int off = 32; off > 0; off >>= 1) s += __shfl_xor(s, off);
        if (tid == 0)
            out[0] = 0.001f * dmat[idx] + s * (1.f / 12800.f);
    }
}

extern "C" void kernel_launch(void* const* d_in, const int* in_sizes, int n_in,
                              void* d_out, int out_size, void* d_ws, size_t ws_size,
                              hipStream_t stream)
{
    const float* feats = (const float*)d_in[0];
    float* out = (float*)d_out;
    float* ws  = (float*)d_ws;

    hipMemsetAsync(d_ws, 0, PBASE * sizeof(float), stream);
    cl_partial<<<dim3(800), dim3(256), 0, stream>>>(feats, ws);
    cl_combine<<<dim3(320), dim3(256), 0, stream>>>(ws);
    cl_final<<<dim3(1), dim3(256), 0, stream>>>(ws, out);
}